// Round 10
// baseline (8098.957 us; speedup 1.0000x reference)
//
#include <hip/hip_runtime.h>
#include <stdint.h>

#define SEQB 512
#define BATCH 32
#define EDIM 256
#define HIDN 256
#define HH2 512
#define RDIM 128
#define NEnt 64
#define NSt 64
#define NNODE 128
#define NHELP 112
#define HPG 14          // helpers per arrive-group (112/8)
#define NROWS 3584      // 1536 (U0) + 1536 (U1) + 512 (Uf)
#define TERMEVT 0xFFFFFFFFu
#define SCOPE_AGENT __HIP_MEMORY_SCOPE_AGENT

static __device__ __forceinline__ float sigm(float x) { return 1.0f / (1.0f + __expf(-x)); }
static __device__ __forceinline__ float tanh_f(float x) { return 1.0f - 2.0f / (__expf(2.0f * x) + 1.0f); }

// ---------------------------------------------------------------------------
// Generic tiled fp32 GEMM: C[m][n] = sum_k Arow(m)[k] * Brow(n)[k] (+ bias[n])
// ---------------------------------------------------------------------------
template<int GATHER>
__global__ __launch_bounds__(256) void gemm_tn(
    const float* __restrict__ A, const int* __restrict__ gidx, const float* __restrict__ gtab,
    const float* __restrict__ B0, const float* __restrict__ B1, int nsplitB,
    const float* __restrict__ bias0, const float* __restrict__ bias1, int nsplitBias,
    float* __restrict__ C, int M, int N, int K)
{
  __shared__ float As[16][68];
  __shared__ float Bs[16][68];
  const int tid = threadIdx.x;
  const int m0 = blockIdx.y * 64, n0 = blockIdx.x * 64;
  const int lr = tid >> 2;
  const int lc = (tid & 3) << 2;
  const float* arow;
  if (GATHER) arow = gtab + (size_t)gidx[m0 + lr] * K;
  else        arow = A + (size_t)(m0 + lr) * K;
  const int bn = n0 + lr;
  const float* brow = (bn < nsplitB) ? (B0 + (size_t)bn * K)
                                     : (B1 + (size_t)(bn - nsplitB) * K);
  const int ty = tid >> 4, tx = tid & 15;
  float acc[4][4] = {};
  for (int k0 = 0; k0 < K; k0 += 16) {
    float4 av = *(const float4*)(arow + k0 + lc);
    float4 bv = *(const float4*)(brow + k0 + lc);
    __syncthreads();
    As[lc + 0][lr] = av.x; As[lc + 1][lr] = av.y; As[lc + 2][lr] = av.z; As[lc + 3][lr] = av.w;
    Bs[lc + 0][lr] = bv.x; Bs[lc + 1][lr] = bv.y; Bs[lc + 2][lr] = bv.z; Bs[lc + 3][lr] = bv.w;
    __syncthreads();
#pragma unroll
    for (int k = 0; k < 16; ++k) {
      const float4 a = *(const float4*)&As[k][ty * 4];
      const float4 b = *(const float4*)&Bs[k][tx * 4];
      acc[0][0] += a.x * b.x; acc[0][1] += a.x * b.y; acc[0][2] += a.x * b.z; acc[0][3] += a.x * b.w;
      acc[1][0] += a.y * b.x; acc[1][1] += a.y * b.y; acc[1][2] += a.y * b.z; acc[1][3] += a.y * b.w;
      acc[2][0] += a.z * b.x; acc[2][1] += a.z * b.y; acc[2][2] += a.z * b.z; acc[2][3] += a.z * b.w;
      acc[3][0] += a.w * b.x; acc[3][1] += a.w * b.y; acc[3][2] += a.w * b.z; acc[3][3] += a.w * b.w;
    }
  }
  float4 bb = make_float4(0.f, 0.f, 0.f, 0.f);
  if (bias0) {
    int n = n0 + tx * 4;
    bb.x = (n + 0 < nsplitBias) ? bias0[n + 0] : bias1[n + 0 - nsplitBias];
    bb.y = (n + 1 < nsplitBias) ? bias0[n + 1] : bias1[n + 1 - nsplitBias];
    bb.z = (n + 2 < nsplitBias) ? bias0[n + 2] : bias1[n + 2 - nsplitBias];
    bb.w = (n + 3 < nsplitBias) ? bias0[n + 3] : bias1[n + 3 - nsplitBias];
  }
#pragma unroll
  for (int i = 0; i < 4; ++i) {
    int m = m0 + ty * 4 + i;
    float4 o;
    o.x = acc[i][0] + bb.x; o.y = acc[i][1] + bb.y; o.z = acc[i][2] + bb.z; o.w = acc[i][3] + bb.w;
    *(float4*)&C[(size_t)m * N + n0 + tx * 4] = o;
  }
}

// ---------------------------------------------------------------------------
// BiLSTM recurrence (unchanged from R9 — tagged qword sync, resident weights).
// ---------------------------------------------------------------------------
__global__ __launch_bounds__(512) void lstm_pair(
    const float* __restrict__ Xg,
    const float* __restrict__ Whh_f, const float* __restrict__ Whh_b,
    unsigned long long* __restrict__ gbuf,   // [2 parity][64 chain][1024] qwords
    float* __restrict__ blstm)
{
  const int tid = threadIdx.x;
  const int pid = blockIdx.x;
  const int half = pid >> 6, chain = pid & 63;
  const int d = chain >> 5, b = chain & 31;
  const int row = half * 512 + tid;

  const float* W = (d ? Whh_b : Whh_f) + (size_t)row * 256;
  float4 w4[64];
#pragma unroll
  for (int i = 0; i < 64; ++i) w4[i] = *(const float4*)(W + 4 * i);

  __shared__ float h_lds[HIDN];
  __shared__ float gsL[512];
  float creg = 0.f;
  if (tid < HIDN) h_lds[tid] = 0.f;
  __syncthreads();

  const float4* h4 = (const float4*)h_lds;
  const int p0 = (half == 0) ? (512 + tid) : tid;
  const int p1 = (half == 0) ? (768 + tid) : (256 + tid);

  for (int it = 0; it < SEQB; ++it) {
    const int t = d ? (SEQB - 1 - it) : it;
    const size_t m = (size_t)t * BATCH + b;
    unsigned long long* gch = gbuf + ((size_t)(it & 1) * 64 + chain) * 1024;
    const float xv = Xg[m * 2048 + (size_t)d * 1024 + row];

    float a0 = 0.f, a1 = 0.f, a2 = 0.f, a3 = 0.f;
#pragma unroll
    for (int i = 0; i < 64; ++i) {
      const float4 hv = h4[i];
      const float4 wv = w4[i];
      a0 += wv.x * hv.x; a1 += wv.y * hv.y; a2 += wv.z * hv.z; a3 += wv.w * hv.w;
    }
    const float gate = (a0 + a1) + (a2 + a3) + xv;
    const unsigned long long pk =
        ((unsigned long long)(unsigned)(it + 1) << 32) |
        (unsigned long long)__float_as_uint(gate);
    __hip_atomic_store(&gch[row], pk, __ATOMIC_RELAXED, SCOPE_AGENT);
    gsL[tid] = gate;
    __syncthreads();
    if (tid < HIDN) {
      const unsigned tg = (unsigned)(it + 1);
      unsigned long long q0, q1;
      do { q0 = __hip_atomic_load(&gch[p0], __ATOMIC_RELAXED, SCOPE_AGENT); }
      while ((unsigned)(q0 >> 32) != tg);
      do { q1 = __hip_atomic_load(&gch[p1], __ATOMIC_RELAXED, SCOPE_AGENT); }
      while ((unsigned)(q1 >> 32) != tg);
      const float pg0 = __uint_as_float((unsigned)q0);
      const float pg1 = __uint_as_float((unsigned)q1);
      float gi, gf, gg, go;
      if (half == 0) { gi = gsL[tid]; gf = gsL[256 + tid]; gg = pg0; go = pg1; }
      else           { gg = gsL[tid]; go = gsL[256 + tid]; gi = pg0; gf = pg1; }
      creg = sigm(gf) * creg + sigm(gi) * tanh_f(gg);
      const float hn = sigm(go) * tanh_f(creg);
      h_lds[tid] = hn;
      if (half == 0) blstm[m * HH2 + (size_t)d * HIDN + tid] = hn;
    }
    __syncthreads();
  }
}

// ---------------------------------------------------------------------------
__global__ __launch_bounds__(256) void attn_k(const float* __restrict__ blstm,
                                              const float* __restrict__ attn_w,
                                              const float* __restrict__ attn_b,
                                              float* __restrict__ attnv)
{
  const int tid = threadIdx.x;
  const int p = blockIdx.x * 4 + (tid >> 6);
  const int lane = tid & 63;
  const size_t base = (size_t)p * HH2 + lane * 8;
  float4 v0 = *(const float4*)&blstm[base];
  float4 v1 = *(const float4*)&blstm[base + 4];
  float4 w0 = *(const float4*)&attn_w[lane * 8];
  float4 w1 = *(const float4*)&attn_w[lane * 8 + 4];
  float acc = v0.x * w0.x + v0.y * w0.y + v0.z * w0.z + v0.w * w0.w
            + v1.x * w1.x + v1.y * w1.y + v1.z * w1.z + v1.w * w1.w;
#pragma unroll
  for (int off = 32; off > 0; off >>= 1) acc += __shfl_down(acc, off);
  if (lane == 0) attnv[p] = acc + attn_b[0];
}

// ---------------------------------------------------------------------------
__global__ __launch_bounds__(64) void entity_prep(const int* __restrict__ spans,
                                                  const float* __restrict__ attnv,
                                                  const float* __restrict__ blstm,
                                                  float* __restrict__ Hent,
                                                  float* __restrict__ P_out)
{
  const int nb = blockIdx.x;
  const int n = nb >> 5, b = nb & 31;
  const int tid = threadIdx.x;
  __shared__ float sc[8];
  if (tid < 8) sc[tid] = attnv[spans[n * 8 + tid] * BATCH + b];
  __syncthreads();
  float mx = sc[0];
#pragma unroll
  for (int w = 1; w < 8; ++w) mx = fmaxf(mx, sc[w]);
  float ex[8]; float ssum = 0.f;
#pragma unroll
  for (int w = 0; w < 8; ++w) { ex[w] = __expf(sc[w] - mx); ssum += ex[w]; }
  float wsum = 0.f;
#pragma unroll
  for (int w = 0; w < 8; ++w) wsum += ex[w] / ssum;
  const size_t base = ((size_t)n * BATCH + b) * HH2;
#pragma unroll
  for (int q = 0; q < 2; ++q) {
    int j = q * 256 + tid * 4;
    float4 v = *(const float4*)&blstm[base + j];
    v.x *= wsum; v.y *= wsum; v.z *= wsum; v.w *= wsum;
    *(float4*)&Hent[base + j] = v;
  }
  if (tid == 0) {
    P_out[((size_t)b * NNODE + n) * 2 + 0] = 0.001f;
    P_out[((size_t)b * NNODE + n) * 2 + 1] = 0.999f;
  }
}

// ---------------------------------------------------------------------------
__global__ void pack_ucat(const float* __restrict__ U_ioc, const float* __restrict__ Uf,
                          float* __restrict__ Ucat)
{
  int j = blockIdx.x, tid = threadIdx.x;
  for (int k = tid; k < 512; k += 128) {
    float v;
    if (j < 1536)      v = U_ioc[(size_t)j * 1024 + k];
    else if (j < 3072) v = U_ioc[(size_t)(j - 1536) * 1024 + 512 + k];
    else               v = Uf[(size_t)(j - 3072) * 512 + k];
    Ucat[(size_t)j * 512 + k] = v;
  }
}

// ---------------------------------------------------------------------------
__global__ __launch_bounds__(256) void elem_pre(const float* __restrict__ W_ioc,
                                                const float* __restrict__ b_ioc,
                                                const float* __restrict__ Wf,
                                                const float* __restrict__ bf,
                                                const float* __restrict__ elem_emb,
                                                float* __restrict__ WiocE,
                                                float* __restrict__ WfE)
{
  const int el = blockIdx.x, tid = threadIdx.x;
  __shared__ float ee[RDIM];
  if (tid < RDIM) ee[tid] = elem_emb[el * RDIM + tid];
  __syncthreads();
  for (int r = tid; r < 1536; r += 256) {
    float acc = b_ioc[r];
#pragma unroll 8
    for (int k = 0; k < RDIM; ++k) acc += W_ioc[(size_t)r * RDIM + k] * ee[k];
    WiocE[(size_t)el * 1536 + r] = acc;
  }
  for (int r = tid; r < 512; r += 256) {
    float acc = bf[r];
#pragma unroll 8
    for (int k = 0; k < RDIM; ++k) acc += Wf[(size_t)r * RDIM + k] * ee[k];
    WfE[(size_t)el * 512 + r] = acc;
  }
}

// ---------------------------------------------------------------------------
__global__ __launch_bounds__(256) void mprep(const float* __restrict__ W1,
                                             const float* __restrict__ b1,
                                             const float* __restrict__ W2,
                                             const float* __restrict__ b2,
                                             float* __restrict__ Mmat,
                                             float* __restrict__ mbv)
{
  const int tid = threadIdx.x;
  for (int j = tid; j < 512; j += 256) {
    float a0 = 0.f, a1 = 0.f;
    for (int m = 0; m < 1024; ++m) {
      float w = W1[(size_t)m * 512 + j];
      a0 += W2[m] * w;
      a1 += W2[1024 + m] * w;
    }
    Mmat[j] = a0; Mmat[512 + j] = a1;
  }
  if (tid < 2) {
    float a = b2[tid];
    for (int m = 0; m < 1024; ++m) a += W2[tid * 1024 + m] * b1[m];
    mbv[tid] = a;
  }
}

// ---------------------------------------------------------------------------
// DAG-LSTM sequential kernel. 113 WGs x 512 threads.
// Helpers unchanged. MASTER: single-wave (64 lanes x 8 elements), ZERO
// barriers in the main loop (wave-synchronous; pst/conf/evtof state in
// registers with runtime-lane __shfl; reductions via shfl_xor). Barrier
// vmcnt(0) drains eliminated -> prefetch truly overlaps the serial chain.
// ---------------------------------------------------------------------------
__global__ __launch_bounds__(512) void dag_seq(
    const int* __restrict__ S, const int* __restrict__ T, const int* __restrict__ EN,
    const int* __restrict__ entsz,
    const float* __restrict__ WiocE, const float* __restrict__ WfE,
    const float* __restrict__ Mmat, const float* __restrict__ mbv,
    float* __restrict__ Tall, float* __restrict__ hbuf,
    uint32_t* head, uint32_t* slotbase, uint32_t* arrive,
    const float* __restrict__ Ucat, float* __restrict__ P_out)
{
  const int tid = threadIdx.x;
  __shared__ int   SL[NSt * BATCH * 2];
  __shared__ int   TLt[NSt * BATCH];
  __shared__ int   ELt[NSt * BATCH];
  __shared__ int   eszL[BATCH];
  __shared__ uint32_t sslot;

  if (blockIdx.x < NHELP) {
    // ----------------------------- helper -----------------------------
    const int w = blockIdx.x;
    const int row = w * 32 + (tid >> 4);
    const int ks = (tid & 15) * 32;
    float wreg[32];
#pragma unroll
    for (int i = 0; i < 8; ++i) {
      float4 v = *(const float4*)&Ucat[(size_t)row * 512 + ks + i * 4];
      wreg[i * 4 + 0] = v.x; wreg[i * 4 + 1] = v.y; wreg[i * 4 + 2] = v.z; wreg[i * 4 + 3] = v.w;
    }
    uint32_t done = 0;
    const int g = w & 7;
    while (true) {
      if (tid == 0) {
        while (__hip_atomic_load(head, __ATOMIC_RELAXED, SCOPE_AGENT) <= done) {
          __builtin_amdgcn_s_sleep(4);
        }
        __builtin_amdgcn_fence(__ATOMIC_ACQUIRE, "agent");
        sslot = slotbase[done];
      }
      __syncthreads();
      const uint32_t slot = sslot;
      if (slot == TERMEVT) break;
      const float* hv = hbuf + (size_t)done * HH2 + ks;
      float acc = 0.f;
#pragma unroll
      for (int i = 0; i < 8; ++i) {
        float4 v = *(const float4*)&hv[i * 4];
        acc += wreg[i * 4 + 0] * v.x + wreg[i * 4 + 1] * v.y
             + wreg[i * 4 + 2] * v.z + wreg[i * 4 + 3] * v.w;
      }
      acc += __shfl_down(acc, 8);
      acc += __shfl_down(acc, 4);
      acc += __shfl_down(acc, 2);
      acc += __shfl_down(acc, 1);
      if ((tid & 15) == 0) {
        __hip_atomic_store(&Tall[(size_t)slot + row], acc, __ATOMIC_RELAXED, SCOPE_AGENT);
      }
      __syncthreads();
      if (tid == 0) {
        __hip_atomic_fetch_add(&arrive[done * 8 + g], 1u, __ATOMIC_RELEASE, SCOPE_AGENT);
      }
      ++done;
    }
    return;
  }

  // ----------------------------- master (single wave) -----------------------------
  for (int i = tid; i < NSt * BATCH * 2; i += 512) SL[i] = S[i];
  for (int i = tid; i < NSt * BATCH; i += 512) { TLt[i] = T[i]; ELt[i] = EN[i]; }
  if (tid < BATCH) eszL[tid] = entsz[tid];
  __syncthreads();
  if (tid >= 64) return;          // wave 0 continues alone; NO barriers below

  const int lane = tid;
  float mm0[8], mm1[8];
#pragma unroll
  for (int i = 0; i < 8; ++i) {
    mm0[i] = Mmat[8 * lane + i];
    mm1[i] = Mmat[512 + 8 * lane + i];
  }
  const float mbv0 = mbv[0], mbv1 = mbv[1];

  uint32_t e = 0;
  float c8[8];
#pragma unroll
  for (int i = 0; i < 8; ++i) c8[i] = 0.f;

#define LOAD8(dst, ptr) do {                                                    \
    const float4 _a = *(const float4*)(ptr);                                    \
    const float4 _b = *(const float4*)((ptr) + 4);                              \
    dst[0] = _a.x; dst[1] = _a.y; dst[2] = _a.z; dst[3] = _a.w;                 \
    dst[4] = _b.x; dst[5] = _b.y; dst[6] = _b.z; dst[7] = _b.w; } while (0)

  for (int b = 0; b < BATCH; ++b) {
    const int esz = eszL[b];
    float pstA = 0.999f;          // node `lane`   (entities, NEnt==64)
    float pstB = 0.f;             // node `64+lane`
    int   confR = 0;              // relation node `lane` projection confirmed
    int   evtofR = 0;             // event id for relation node `lane`

    bool  pfok = false;
    float pt[8][8], pw[4][8];
    int nx_a0 = 0, nx_a1 = 0, nx_tgt = 0, nx_el = -1;

#define PFETCH(sn) do {                                                         \
      pfok = false;                                                             \
      if ((sn) < NSt) {                                                         \
        const int sbn_ = (sn) * BATCH + b;                                      \
        nx_a0 = SL[2 * sbn_]; nx_a1 = SL[2 * sbn_ + 1];                         \
        nx_tgt = TLt[sbn_];   nx_el = ELt[sbn_];                                \
        if (nx_el >= 0) {                                                       \
          const float* nwe_ = WiocE + (size_t)nx_el * 1536;                     \
          const float* nwf_ = WfE + (size_t)nx_el * 512;                        \
          LOAD8(pw[0], nwe_ + 8 * lane);                                        \
          LOAD8(pw[1], nwe_ + 512 + 8 * lane);                                  \
          LOAD8(pw[2], nwe_ + 1024 + 8 * lane);                                 \
          LOAD8(pw[3], nwf_ + 8 * lane);                                        \
        }                                                                       \
        const int cf0_ = __shfl(confR, nx_a0 & 63);                             \
        const int cf1_ = __shfl(confR, nx_a1 & 63);                             \
        const bool ok0_ = (nx_a0 < NEnt) || (cf0_ != 0);                        \
        const bool ok1_ = (nx_a1 < NEnt) || (cf1_ != 0);                        \
        if (ok0_ && ok1_) {                                                     \
          const size_t ns0_ = ((size_t)nx_a0 * BATCH + b) * NROWS;              \
          const size_t ns1_ = ((size_t)nx_a1 * BATCH + b) * NROWS;              \
          LOAD8(pt[0], Tall + ns0_ + 8 * lane);                                 \
          LOAD8(pt[1], Tall + ns1_ + 1536 + 8 * lane);                          \
          LOAD8(pt[2], Tall + ns0_ + 512 + 8 * lane);                           \
          LOAD8(pt[3], Tall + ns1_ + 2048 + 8 * lane);                          \
          LOAD8(pt[4], Tall + ns0_ + 1024 + 8 * lane);                          \
          LOAD8(pt[5], Tall + ns1_ + 2560 + 8 * lane);                          \
          LOAD8(pt[6], Tall + ns0_ + 3072 + 8 * lane);                          \
          LOAD8(pt[7], Tall + ns1_ + 3072 + 8 * lane);                          \
          pfok = true;                                                          \
        }                                                                       \
      }                                                                         \
    } while (0)

    PFETCH(0);

    for (int s = 0; s < NSt; ++s) {
      const int a0 = nx_a0, a1 = nx_a1, tgt = nx_tgt, el = nx_el;
      const bool valid = (tgt >= esz) && (el > -1);
      const float sA0 = __shfl(pstA, a0 & 63), sB0 = __shfl(pstB, a0 & 63);
      const float sA1 = __shfl(pstA, a1 & 63), sB1 = __shfl(pstB, a1 & 63);
      const float pa0 = (a0 < 64) ? sA0 : sB0;
      const float pa1 = (a1 < 64) ? sA1 : sB1;
      const bool cond = valid && (pa0 > 0.5f) && (pa1 > 0.5f);
      float o0, o1;
      if (cond) {
        if (!pfok) {
          // slow path: confirm helper projections for relation args
          const int r0 = (a0 >= NEnt) ? (a0 - NEnt) : -1;
          const int r1 = (a1 >= NEnt) ? (a1 - NEnt) : -1;
          const int cf0 = __shfl(confR, a0 & 63);
          const int cf1 = __shfl(confR, a1 & 63);
          const int ev0 = __shfl(evtofR, a0 & 63);
          const int ev1 = __shfl(evtofR, a1 & 63);
          if (lane < 8 && r0 >= 0 && !cf0) {
            while (__hip_atomic_load(&arrive[(uint32_t)ev0 * 8 + lane],
                                     __ATOMIC_RELAXED, SCOPE_AGENT) < (uint32_t)HPG) {
              __builtin_amdgcn_s_sleep(1);
            }
          }
          if (lane >= 8 && lane < 16 && r1 >= 0 && !cf1) {
            while (__hip_atomic_load(&arrive[(uint32_t)ev1 * 8 + (lane - 8)],
                                     __ATOMIC_RELAXED, SCOPE_AGENT) < (uint32_t)HPG) {
              __builtin_amdgcn_s_sleep(1);
            }
          }
          __builtin_amdgcn_fence(__ATOMIC_ACQUIRE, "agent");
          if (lane == r0 || lane == r1) confR = 1;
          const size_t s0 = ((size_t)a0 * BATCH + b) * NROWS;
          const size_t s1 = ((size_t)a1 * BATCH + b) * NROWS;
          LOAD8(pt[0], Tall + s0 + 8 * lane);
          LOAD8(pt[1], Tall + s1 + 1536 + 8 * lane);
          LOAD8(pt[2], Tall + s0 + 512 + 8 * lane);
          LOAD8(pt[3], Tall + s1 + 2048 + 8 * lane);
          LOAD8(pt[4], Tall + s0 + 1024 + 8 * lane);
          LOAD8(pt[5], Tall + s1 + 2560 + 8 * lane);
          LOAD8(pt[6], Tall + s0 + 3072 + 8 * lane);
          LOAD8(pt[7], Tall + s1 + 3072 + 8 * lane);
        }
        float hv8[8];
        float l0 = 0.f, l1 = 0.f;
#pragma unroll
        for (int i = 0; i < 8; ++i) {
          const float ii = pw[0][i] + pt[0][i] + pt[1][i];
          const float oo = pw[1][i] + pt[2][i] + pt[3][i];
          const float ch = pw[2][i] + pt[4][i] + pt[5][i];
          const float f0 = sigm(pw[3][i] + pt[6][i]);
          const float f1 = sigm(pw[3][i] + pt[7][i]);
          float cn = (f0 + f1) * c8[i] + sigm(ii) * tanh_f(ch);
          cn = fminf(fmaxf(cn, -100.f), 100.f);
          float hh = sigm(oo) * tanh_f(cn);
          hh = fminf(fmaxf(hh, -100.f), 100.f);
          c8[i] = cn; hv8[i] = hh;
          l0 += mm0[i] * hh; l1 += mm1[i] * hh;
        }
        PFETCH(s + 1);     // overlap next step's loads with reduce/softmax
#pragma unroll
        for (int off = 32; off > 0; off >>= 1) {
          l0 += __shfl_xor(l0, off);
          l1 += __shfl_xor(l1, off);
        }
        const float L0 = l0 + mbv0, L1 = l1 + mbv1;
        const float mx = fmaxf(L0, L1);
        const float e0 = __expf(L0 - mx), e1x = __expf(L1 - mx);
        const float inv = 1.f / (e0 + e1x);
        o0 = e0 * inv; o1 = e1x * inv;
        const bool pub = (o1 > 0.5f) && (tgt < NEnt + 32);
        if (pub) {
          float4 v0 = make_float4(hv8[0], hv8[1], hv8[2], hv8[3]);
          float4 v1 = make_float4(hv8[4], hv8[5], hv8[6], hv8[7]);
          *(float4*)&hbuf[(size_t)e * HH2 + 8 * lane] = v0;
          *(float4*)&hbuf[(size_t)e * HH2 + 8 * lane + 4] = v1;
          if (lane == (tgt - NEnt)) evtofR = (int)e;
          if (lane == 0) {
            __hip_atomic_store(&slotbase[e],
                (uint32_t)(((uint32_t)tgt * BATCH + (uint32_t)b) * NROWS),
                __ATOMIC_RELAXED, SCOPE_AGENT);
            __hip_atomic_store(head, e + 1u, __ATOMIC_RELEASE, SCOPE_AGENT);
          }
          ++e;
        }
      } else {
        o0 = valid ? 0.999f : ((tgt < NEnt) ? 0.001f : 0.f);
        o1 = valid ? 0.001f : ((tgt < NEnt) ? 0.999f : 0.f);
        PFETCH(s + 1);
      }
      if (lane == 0 && (valid || tgt >= NEnt)) {
        P_out[((size_t)b * NNODE + tgt) * 2 + 0] = o0;
        P_out[((size_t)b * NNODE + tgt) * 2 + 1] = o1;
      }
      if (valid) {
        if (tgt < 64) { if (lane == tgt) pstA = o1; }
        else          { if (lane == (tgt - 64)) pstB = o1; }
      }
    }
#undef PFETCH
  }
#undef LOAD8
  if (lane == 0) {
    __hip_atomic_store(&slotbase[e], TERMEVT, __ATOMIC_RELAXED, SCOPE_AGENT);
    __hip_atomic_store(head, e + 1u, __ATOMIC_RELEASE, SCOPE_AGENT);
  }
}

// ---------------------------------------------------------------------------
extern "C" void kernel_launch(void* const* d_in, const int* in_sizes, int n_in,
                              void* d_out, int out_size, void* d_ws, size_t ws_size,
                              hipStream_t stream)
{
  const int* tokens = (const int*)d_in[0];
  const int* spans  = (const int*)d_in[1];
  const int* enames = (const int*)d_in[2];
  const int* T      = (const int*)d_in[5];
  const int* S      = (const int*)d_in[6];
  const int* entsz  = (const int*)d_in[7];
  const float* word_emb = (const float*)d_in[8];
  const float* elem_emb = (const float*)d_in[9];
  const float* attn_w = (const float*)d_in[10];
  const float* attn_b = (const float*)d_in[11];
  const float* Wih_f = (const float*)d_in[12];
  const float* Whh_f = (const float*)d_in[13];
  const float* bl_f  = (const float*)d_in[14];
  const float* Wih_b = (const float*)d_in[15];
  const float* Whh_b = (const float*)d_in[16];
  const float* bl_b  = (const float*)d_in[17];
  const float* W_ioc = (const float*)d_in[18];
  const float* U_ioc = (const float*)d_in[19];
  const float* b_ioc = (const float*)d_in[20];
  const float* Wf    = (const float*)d_in[21];
  const float* Uf    = (const float*)d_in[22];
  const float* bf    = (const float*)d_in[23];
  const float* W1    = (const float*)d_in[24];
  const float* b1    = (const float*)d_in[25];
  const float* W2    = (const float*)d_in[26];
  const float* b2    = (const float*)d_in[27];
  float* P_out = (float*)d_out;

  char* ws = (char*)d_ws;
  uint32_t* head     = (uint32_t*)ws;                    // @0
  uint32_t* slotbase = (uint32_t*)(ws + 8192);           // 1024 u32
  uint32_t* arrive   = (uint32_t*)(ws + 16384);          // 8*1024 u32 = 32KB
  float* fws = (float*)(ws + 65536);
  size_t off = 0;
  float* Xg    = fws + off; off += (size_t)16384 * 2048;
  float* blstm = fws + off; off += (size_t)SEQB * BATCH * HH2;
  float* attnv = fws + off; off += (size_t)SEQB * BATCH;
  float* Hent  = fws + off; off += (size_t)2048 * 512;
  float* Tall  = fws + off; off += (size_t)96 * BATCH * NROWS;
  unsigned long long* gbuf = (unsigned long long*)(fws + off);
  off += (size_t)2 * 64 * 1024 * 2;          // qwords = 2 floats each
  float* Ucat  = fws + off; off += (size_t)NROWS * 512;
  float* WiocE = fws + off; off += (size_t)128 * 1536;
  float* WfE   = fws + off; off += (size_t)128 * 512;
  float* Mmat  = fws + off; off += 1024;
  float* mbv   = fws + off; off += 16;
  float* hbuf  = fws + off; off += (size_t)1024 * 512;
  const size_t needed = 65536 + off * sizeof(float);
  if (ws_size < needed) return;   // workspace too small: bail (visible failure)

  hipMemsetAsync(d_ws, 0, 65536, stream);

  // 1) Xg = gather(word_emb, tokens) @ [Wih_f;Wih_b].T + [bl_f;bl_b]
  gemm_tn<1><<<dim3(2048 / 64, 16384 / 64), 256, 0, stream>>>(
      nullptr, tokens, word_emb, Wih_f, Wih_b, 1024, bl_f, bl_b, 1024,
      Xg, 16384, 2048, 256);

  // 2) recurrent BiLSTM (R5 pair structure + tagged single-round sync)
  lstm_pair<<<128, 512, 0, stream>>>(Xg, Whh_f, Whh_b, gbuf, blstm);

  // 3) attention scores + entity H
  attn_k<<<4096, 256, 0, stream>>>(blstm, attn_w, attn_b, attnv);
  entity_prep<<<2048, 64, 0, stream>>>(spans, attnv, blstm, Hent, P_out);

  // 4) DAG-LSTM precompute
  pack_ucat<<<NROWS, 128, 0, stream>>>(U_ioc, Uf, Ucat);
  elem_pre<<<128, 256, 0, stream>>>(W_ioc, b_ioc, Wf, bf, elem_emb, WiocE, WfE);
  mprep<<<1, 256, 0, stream>>>(W1, b1, W2, b2, Mmat, mbv);
  gemm_tn<0><<<dim3(NROWS / 64, 2048 / 64), 256, 0, stream>>>(
      Hent, nullptr, nullptr, Ucat, nullptr, 0x40000000, nullptr, nullptr, 0,
      Tall, 2048, NROWS, 512);

  // 5) sequential DAG-LSTM with helper projection grid
  dag_seq<<<NHELP + 1, 512, 0, stream>>>(S, T, enames, entsz, WiocE, WfE, Mmat, mbv,
                                         Tall, hbuf, head, slotbase, arrive, Ucat, P_out);
}

// Round 11
// 6690.759 us; speedup vs baseline: 1.2105x; 1.2105x over previous
//
#include <hip/hip_runtime.h>
#include <stdint.h>

#define SEQB 512
#define BATCH 32
#define EDIM 256
#define HIDN 256
#define HH2 512
#define RDIM 128
#define NEnt 64
#define NSt 64
#define NNODE 128
#define NHELP 112
#define HPG 14          // helpers per arrive-group (112/8)
#define NROWS 3584      // 1536 (U0) + 1536 (U1) + 512 (Uf)
#define TERMEVT 0xFFFFFFFFu
#define SCOPE_AGENT __HIP_MEMORY_SCOPE_AGENT

static __device__ __forceinline__ float sigm(float x) { return 1.0f / (1.0f + __expf(-x)); }
static __device__ __forceinline__ float tanh_f(float x) { return 1.0f - 2.0f / (__expf(2.0f * x) + 1.0f); }

// ---------------------------------------------------------------------------
// Generic tiled fp32 GEMM: C[m][n] = sum_k Arow(m)[k] * Brow(n)[k] (+ bias[n])
// ---------------------------------------------------------------------------
template<int GATHER>
__global__ __launch_bounds__(256) void gemm_tn(
    const float* __restrict__ A, const int* __restrict__ gidx, const float* __restrict__ gtab,
    const float* __restrict__ B0, const float* __restrict__ B1, int nsplitB,
    const float* __restrict__ bias0, const float* __restrict__ bias1, int nsplitBias,
    float* __restrict__ C, int M, int N, int K)
{
  __shared__ float As[16][68];
  __shared__ float Bs[16][68];
  const int tid = threadIdx.x;
  const int m0 = blockIdx.y * 64, n0 = blockIdx.x * 64;
  const int lr = tid >> 2;
  const int lc = (tid & 3) << 2;
  const float* arow;
  if (GATHER) arow = gtab + (size_t)gidx[m0 + lr] * K;
  else        arow = A + (size_t)(m0 + lr) * K;
  const int bn = n0 + lr;
  const float* brow = (bn < nsplitB) ? (B0 + (size_t)bn * K)
                                     : (B1 + (size_t)(bn - nsplitB) * K);
  const int ty = tid >> 4, tx = tid & 15;
  float acc[4][4] = {};
  for (int k0 = 0; k0 < K; k0 += 16) {
    float4 av = *(const float4*)(arow + k0 + lc);
    float4 bv = *(const float4*)(brow + k0 + lc);
    __syncthreads();
    As[lc + 0][lr] = av.x; As[lc + 1][lr] = av.y; As[lc + 2][lr] = av.z; As[lc + 3][lr] = av.w;
    Bs[lc + 0][lr] = bv.x; Bs[lc + 1][lr] = bv.y; Bs[lc + 2][lr] = bv.z; Bs[lc + 3][lr] = bv.w;
    __syncthreads();
#pragma unroll
    for (int k = 0; k < 16; ++k) {
      const float4 a = *(const float4*)&As[k][ty * 4];
      const float4 b = *(const float4*)&Bs[k][tx * 4];
      acc[0][0] += a.x * b.x; acc[0][1] += a.x * b.y; acc[0][2] += a.x * b.z; acc[0][3] += a.x * b.w;
      acc[1][0] += a.y * b.x; acc[1][1] += a.y * b.y; acc[1][2] += a.y * b.z; acc[1][3] += a.y * b.w;
      acc[2][0] += a.z * b.x; acc[2][1] += a.z * b.y; acc[2][2] += a.z * b.z; acc[2][3] += a.z * b.w;
      acc[3][0] += a.w * b.x; acc[3][1] += a.w * b.y; acc[3][2] += a.w * b.z; acc[3][3] += a.w * b.w;
    }
  }
  float4 bb = make_float4(0.f, 0.f, 0.f, 0.f);
  if (bias0) {
    int n = n0 + tx * 4;
    bb.x = (n + 0 < nsplitBias) ? bias0[n + 0] : bias1[n + 0 - nsplitBias];
    bb.y = (n + 1 < nsplitBias) ? bias0[n + 1] : bias1[n + 1 - nsplitBias];
    bb.z = (n + 2 < nsplitBias) ? bias0[n + 2] : bias1[n + 2 - nsplitBias];
    bb.w = (n + 3 < nsplitBias) ? bias0[n + 3] : bias1[n + 3 - nsplitBias];
  }
#pragma unroll
  for (int i = 0; i < 4; ++i) {
    int m = m0 + ty * 4 + i;
    float4 o;
    o.x = acc[i][0] + bb.x; o.y = acc[i][1] + bb.y; o.z = acc[i][2] + bb.z; o.w = acc[i][3] + bb.w;
    *(float4*)&C[(size_t)m * N + n0 + tx * 4] = o;
  }
}

// ---------------------------------------------------------------------------
// BiLSTM recurrence: ELEMENT-split pair with R9's proven-resident loop shape.
// Each WG owns 128 elements with ALL 4 gates (thread = gate row g*256+elem,
// full k-range 0..256: w4[0..63], constant indices only, no runtime offset).
// Cell update uses only LOCAL gates (LDS). Cross-WG exchange = 128 tagged
// h qwords (tag in high 32 bits), parity double-buffered; poll at loop top.
// ---------------------------------------------------------------------------
__global__ __launch_bounds__(512) void lstm_esplit(
    const float* __restrict__ Xg,
    const float* __restrict__ Whh_f, const float* __restrict__ Whh_b,
    unsigned long long* __restrict__ hxbuf,  // [2 parity][64 chain][256] qwords
    float* __restrict__ blstm)
{
  const int tid = threadIdx.x;
  const int pid = blockIdx.x;
  const int hf = pid >> 6, chain = pid & 63;   // peer WG = pid^64 (same XCD slot)
  const int d = chain >> 5, b = chain & 31;
  const int j = tid & 127;              // element within own half
  const int g = tid >> 7;               // gate 0=i,1=f,2=g,3=o
  const int elem = hf * 128 + j;        // element 0..255
  const int grow = g * 256 + elem;      // global gate row 0..1023

  const float* W = (d ? Whh_b : Whh_f) + (size_t)grow * 256;
  float4 w4[64];
#pragma unroll
  for (int i = 0; i < 64; ++i) w4[i] = *(const float4*)(W + 4 * i);

  __shared__ float h_lds[HIDN];
  __shared__ float gsL[512];
  float creg = 0.f;                     // cell for element `elem` (threads tid<128)
  if (tid < HIDN) h_lds[tid] = 0.f;
  __syncthreads();

  const float4* h4 = (const float4*)h_lds;
  const int peerbase = (1 - hf) * 128;
  const size_t xgoff = (size_t)d * 1024 + grow;

  for (int it = 0; it < SEQB; ++it) {
    const int t = d ? (SEQB - 1 - it) : it;
    const size_t m = (size_t)t * BATCH + b;
    const float xv = Xg[m * 2048 + xgoff];   // overlaps the poll below

    // --- poll peer h-half (tag == it; zero-init covers it=0) ---
    if (tid < 128) {
      const unsigned long long* src =
          &hxbuf[((size_t)(it & 1) * 64 + chain) * 256 + peerbase + tid];
      unsigned long long q;
      do { q = __hip_atomic_load(src, __ATOMIC_RELAXED, SCOPE_AGENT); }
      while ((unsigned)(q >> 32) != (unsigned)it);
      h_lds[peerbase + tid] = __uint_as_float((unsigned)q);
    }
    __syncthreads();

    // --- full MAC, straight-line, constant w4 indices ---
    float a0 = 0.f, a1 = 0.f, a2 = 0.f, a3 = 0.f;
#pragma unroll
    for (int i = 0; i < 64; ++i) {
      const float4 hv = h4[i];               // wave-uniform -> LDS broadcast
      const float4 wv = w4[i];
      a0 += wv.x * hv.x; a1 += wv.y * hv.y; a2 += wv.z * hv.z; a3 += wv.w * hv.w;
    }
    gsL[tid] = (a0 + a1) + (a2 + a3) + xv;   // gate g of element elem at [g*128+j]
    __syncthreads();

    // --- cell update for own 128 elements (all gates LOCAL) ---
    if (tid < 128) {
      const float gi = gsL[tid], gf = gsL[128 + tid];
      const float gg = gsL[256 + tid], go = gsL[384 + tid];
      creg = sigm(gf) * creg + sigm(gi) * tanh_f(gg);
      const float hn = sigm(go) * tanh_f(creg);
      h_lds[elem] = hn;
      const unsigned long long pk =
          ((unsigned long long)(unsigned)(it + 1) << 32) |
          (unsigned long long)__float_as_uint(hn);
      __hip_atomic_store(&hxbuf[((size_t)((it + 1) & 1) * 64 + chain) * 256 + elem], pk,
                         __ATOMIC_RELAXED, SCOPE_AGENT);
      blstm[m * HH2 + (size_t)d * HIDN + elem] = hn;
    }
    __syncthreads();
  }
}

// ---------------------------------------------------------------------------
__global__ __launch_bounds__(256) void attn_k(const float* __restrict__ blstm,
                                              const float* __restrict__ attn_w,
                                              const float* __restrict__ attn_b,
                                              float* __restrict__ attnv)
{
  const int tid = threadIdx.x;
  const int p = blockIdx.x * 4 + (tid >> 6);
  const int lane = tid & 63;
  const size_t base = (size_t)p * HH2 + lane * 8;
  float4 v0 = *(const float4*)&blstm[base];
  float4 v1 = *(const float4*)&blstm[base + 4];
  float4 w0 = *(const float4*)&attn_w[lane * 8];
  float4 w1 = *(const float4*)&attn_w[lane * 8 + 4];
  float acc = v0.x * w0.x + v0.y * w0.y + v0.z * w0.z + v0.w * w0.w
            + v1.x * w1.x + v1.y * w1.y + v1.z * w1.z + v1.w * w1.w;
#pragma unroll
  for (int off = 32; off > 0; off >>= 1) acc += __shfl_down(acc, off);
  if (lane == 0) attnv[p] = acc + attn_b[0];
}

// ---------------------------------------------------------------------------
__global__ __launch_bounds__(64) void entity_prep(const int* __restrict__ spans,
                                                  const float* __restrict__ attnv,
                                                  const float* __restrict__ blstm,
                                                  float* __restrict__ Hent,
                                                  float* __restrict__ P_out)
{
  const int nb = blockIdx.x;
  const int n = nb >> 5, b = nb & 31;
  const int tid = threadIdx.x;
  __shared__ float sc[8];
  if (tid < 8) sc[tid] = attnv[spans[n * 8 + tid] * BATCH + b];
  __syncthreads();
  float mx = sc[0];
#pragma unroll
  for (int w = 1; w < 8; ++w) mx = fmaxf(mx, sc[w]);
  float ex[8]; float ssum = 0.f;
#pragma unroll
  for (int w = 0; w < 8; ++w) { ex[w] = __expf(sc[w] - mx); ssum += ex[w]; }
  float wsum = 0.f;
#pragma unroll
  for (int w = 0; w < 8; ++w) wsum += ex[w] / ssum;
  const size_t base = ((size_t)n * BATCH + b) * HH2;
#pragma unroll
  for (int q = 0; q < 2; ++q) {
    int j = q * 256 + tid * 4;
    float4 v = *(const float4*)&blstm[base + j];
    v.x *= wsum; v.y *= wsum; v.z *= wsum; v.w *= wsum;
    *(float4*)&Hent[base + j] = v;
  }
  if (tid == 0) {
    P_out[((size_t)b * NNODE + n) * 2 + 0] = 0.001f;
    P_out[((size_t)b * NNODE + n) * 2 + 1] = 0.999f;
  }
}

// ---------------------------------------------------------------------------
__global__ void pack_ucat(const float* __restrict__ U_ioc, const float* __restrict__ Uf,
                          float* __restrict__ Ucat)
{
  int j = blockIdx.x, tid = threadIdx.x;
  for (int k = tid; k < 512; k += 128) {
    float v;
    if (j < 1536)      v = U_ioc[(size_t)j * 1024 + k];
    else if (j < 3072) v = U_ioc[(size_t)(j - 1536) * 1024 + 512 + k];
    else               v = Uf[(size_t)(j - 3072) * 512 + k];
    Ucat[(size_t)j * 512 + k] = v;
  }
}

// ---------------------------------------------------------------------------
__global__ __launch_bounds__(256) void elem_pre(const float* __restrict__ W_ioc,
                                                const float* __restrict__ b_ioc,
                                                const float* __restrict__ Wf,
                                                const float* __restrict__ bf,
                                                const float* __restrict__ elem_emb,
                                                float* __restrict__ WiocE,
                                                float* __restrict__ WfE)
{
  const int el = blockIdx.x, tid = threadIdx.x;
  __shared__ float ee[RDIM];
  if (tid < RDIM) ee[tid] = elem_emb[el * RDIM + tid];
  __syncthreads();
  for (int r = tid; r < 1536; r += 256) {
    float acc = b_ioc[r];
#pragma unroll 8
    for (int k = 0; k < RDIM; ++k) acc += W_ioc[(size_t)r * RDIM + k] * ee[k];
    WiocE[(size_t)el * 1536 + r] = acc;
  }
  for (int r = tid; r < 512; r += 256) {
    float acc = bf[r];
#pragma unroll 8
    for (int k = 0; k < RDIM; ++k) acc += Wf[(size_t)r * RDIM + k] * ee[k];
    WfE[(size_t)el * 512 + r] = acc;
  }
}

// ---------------------------------------------------------------------------
__global__ __launch_bounds__(256) void mprep(const float* __restrict__ W1,
                                             const float* __restrict__ b1,
                                             const float* __restrict__ W2,
                                             const float* __restrict__ b2,
                                             float* __restrict__ Mmat,
                                             float* __restrict__ mbv)
{
  const int tid = threadIdx.x;
  for (int j = tid; j < 512; j += 256) {
    float a0 = 0.f, a1 = 0.f;
    for (int m = 0; m < 1024; ++m) {
      float w = W1[(size_t)m * 512 + j];
      a0 += W2[m] * w;
      a1 += W2[1024 + m] * w;
    }
    Mmat[j] = a0; Mmat[512 + j] = a1;
  }
  if (tid < 2) {
    float a = b2[tid];
    for (int m = 0; m < 1024; ++m) a += W2[tid * 1024 + m] * b1[m];
    mbv[tid] = a;
  }
}

// ---------------------------------------------------------------------------
// DAG-LSTM sequential kernel — REVERTED verbatim to the R9 version (3.09 ms,
// best measured). 113 WGs x 512 threads.
// ---------------------------------------------------------------------------
__global__ __launch_bounds__(512) void dag_seq(
    const int* __restrict__ S, const int* __restrict__ T, const int* __restrict__ EN,
    const int* __restrict__ entsz,
    const float* __restrict__ WiocE, const float* __restrict__ WfE,
    const float* __restrict__ Mmat, const float* __restrict__ mbv,
    float* __restrict__ Tall, float* __restrict__ hbuf,
    uint32_t* head, uint32_t* slotbase, uint32_t* arrive,
    const float* __restrict__ Ucat, float* __restrict__ P_out)
{
  const int tid = threadIdx.x;
  __shared__ int   SL[NSt * BATCH * 2];
  __shared__ int   TLt[NSt * BATCH];
  __shared__ int   ELt[NSt * BATCH];
  __shared__ int   eszL[BATCH];
  __shared__ float MmatL[1024];
  __shared__ float mbvL[2];
  __shared__ float pstL[NNODE];
  __shared__ int   evtofL[NSt];
  __shared__ int   confL[NSt];
  __shared__ float red0[8], red1[8], bcast[2];
  __shared__ uint32_t sslot;

  if (blockIdx.x < NHELP) {
    const int w = blockIdx.x;
    const int row = w * 32 + (tid >> 4);
    const int ks = (tid & 15) * 32;
    float wreg[32];
#pragma unroll
    for (int i = 0; i < 8; ++i) {
      float4 v = *(const float4*)&Ucat[(size_t)row * 512 + ks + i * 4];
      wreg[i * 4 + 0] = v.x; wreg[i * 4 + 1] = v.y; wreg[i * 4 + 2] = v.z; wreg[i * 4 + 3] = v.w;
    }
    uint32_t done = 0;
    const int g = w & 7;
    while (true) {
      if (tid == 0) {
        while (__hip_atomic_load(head, __ATOMIC_RELAXED, SCOPE_AGENT) <= done) {
          __builtin_amdgcn_s_sleep(4);
        }
        __builtin_amdgcn_fence(__ATOMIC_ACQUIRE, "agent");
        sslot = slotbase[done];
      }
      __syncthreads();
      const uint32_t slot = sslot;
      if (slot == TERMEVT) break;
      const float* hv = hbuf + (size_t)done * HH2 + ks;
      float acc = 0.f;
#pragma unroll
      for (int i = 0; i < 8; ++i) {
        float4 v = *(const float4*)&hv[i * 4];
        acc += wreg[i * 4 + 0] * v.x + wreg[i * 4 + 1] * v.y
             + wreg[i * 4 + 2] * v.z + wreg[i * 4 + 3] * v.w;
      }
      acc += __shfl_down(acc, 8);
      acc += __shfl_down(acc, 4);
      acc += __shfl_down(acc, 2);
      acc += __shfl_down(acc, 1);
      if ((tid & 15) == 0) {
        __hip_atomic_store(&Tall[(size_t)slot + row], acc, __ATOMIC_RELAXED, SCOPE_AGENT);
      }
      __syncthreads();
      if (tid == 0) {
        __hip_atomic_fetch_add(&arrive[done * 8 + g], 1u, __ATOMIC_RELEASE, SCOPE_AGENT);
      }
      ++done;
    }
    return;
  }

  // master
  for (int i = tid; i < NSt * BATCH * 2; i += 512) SL[i] = S[i];
  for (int i = tid; i < NSt * BATCH; i += 512) { TLt[i] = T[i]; ELt[i] = EN[i]; }
  for (int i = tid; i < 1024; i += 512) MmatL[i] = Mmat[i];
  if (tid < BATCH) eszL[tid] = entsz[tid];
  if (tid < 2) mbvL[tid] = mbv[tid];
  __syncthreads();

  float c = 0.f;
  uint32_t e = 0;
  for (int b = 0; b < BATCH; ++b) {
    const int esz = eszL[b];
    for (int j = tid; j < NNODE; j += 512) pstL[j] = (j < NEnt) ? 0.999f : 0.f;
    if (tid < NSt) confL[tid] = 0;
    __syncthreads();

    bool  pfok = false;
    float pt0 = 0.f, pt1 = 0.f, pt2 = 0.f, pt3 = 0.f, pt4 = 0.f, pt5 = 0.f, pt6 = 0.f, pt7 = 0.f;
    float pw0 = 0.f, pw1 = 0.f, pw2 = 0.f, pwf = 0.f;

#define PFETCH(sn)                                                              \
    do {                                                                        \
      pfok = false;                                                             \
      if ((sn) < NSt) {                                                         \
        const int sbn_ = (sn) * BATCH + b;                                      \
        const int na0_ = SL[2 * sbn_], na1_ = SL[2 * sbn_ + 1];                 \
        const int nel_ = ELt[sbn_];                                             \
        if (nel_ >= 0) {                                                        \
          const float* nwe_ = WiocE + (size_t)nel_ * 1536;                      \
          const float* nwf_ = WfE + (size_t)nel_ * 512;                         \
          pw0 = nwe_[tid]; pw1 = nwe_[512 + tid]; pw2 = nwe_[1024 + tid];       \
          pwf = nwf_[tid];                                                      \
        }                                                                       \
        const bool ok0_ = (na0_ < NEnt) || (confL[na0_ - NEnt] != 0);           \
        const bool ok1_ = (na1_ < NEnt) || (confL[na1_ - NEnt] != 0);           \
        if (ok0_ && ok1_) {                                                     \
          const size_t ns0_ = ((size_t)na0_ * BATCH + b) * NROWS;               \
          const size_t ns1_ = ((size_t)na1_ * BATCH + b) * NROWS;               \
          pt0 = Tall[ns0_ + tid];               pt1 = Tall[ns1_ + 1536 + tid];  \
          pt2 = Tall[ns0_ + 512 + tid];         pt3 = Tall[ns1_ + 2048 + tid];  \
          pt4 = Tall[ns0_ + 1024 + tid];        pt5 = Tall[ns1_ + 2560 + tid];  \
          pt6 = Tall[ns0_ + 3072 + tid];        pt7 = Tall[ns1_ + 3072 + tid];  \
          pfok = true;                                                          \
        }                                                                       \
      }                                                                         \
    } while (0)

    PFETCH(0);

    for (int s = 0; s < NSt; ++s) {
      const int sb = s * BATCH + b;
      const int a0 = SL[2 * sb], a1 = SL[2 * sb + 1];
      const int tgt = TLt[sb], el = ELt[sb];
      const bool valid = (tgt >= esz) && (el > -1);
      const float pa0 = pstL[a0], pa1 = pstL[a1];
      const bool cond = valid && (pa0 > 0.5f) && (pa1 > 0.5f);
      if (cond) {
        if (!pfok) {
          const int r0 = (a0 >= NEnt) ? (a0 - NEnt) : -1;
          const int r1 = (a1 >= NEnt) ? (a1 - NEnt) : -1;
          if (tid < 8 && r0 >= 0 && !confL[r0]) {
            const uint32_t ev = (uint32_t)evtofL[r0];
            while (__hip_atomic_load(&arrive[ev * 8 + tid], __ATOMIC_RELAXED, SCOPE_AGENT)
                   < (uint32_t)HPG) { __builtin_amdgcn_s_sleep(1); }
          }
          if (tid >= 8 && tid < 16 && r1 >= 0 && !confL[r1]) {
            const uint32_t ev = (uint32_t)evtofL[r1];
            while (__hip_atomic_load(&arrive[ev * 8 + (tid - 8)], __ATOMIC_RELAXED, SCOPE_AGENT)
                   < (uint32_t)HPG) { __builtin_amdgcn_s_sleep(1); }
          }
          __syncthreads();
          if (tid == 0) {
            __builtin_amdgcn_fence(__ATOMIC_ACQUIRE, "agent");
            if (r0 >= 0) confL[r0] = 1;
            if (r1 >= 0) confL[r1] = 1;
          }
          __syncthreads();
          const size_t s0 = ((size_t)a0 * BATCH + b) * NROWS;
          const size_t s1 = ((size_t)a1 * BATCH + b) * NROWS;
          pt0 = Tall[s0 + tid];        pt1 = Tall[s1 + 1536 + tid];
          pt2 = Tall[s0 + 512 + tid];  pt3 = Tall[s1 + 2048 + tid];
          pt4 = Tall[s0 + 1024 + tid]; pt5 = Tall[s1 + 2560 + tid];
          pt6 = Tall[s0 + 3072 + tid]; pt7 = Tall[s1 + 3072 + tid];
        }
        const float ii = pw0 + pt0 + pt1;
        const float oo = pw1 + pt2 + pt3;
        const float ch = pw2 + pt4 + pt5;
        const float f0 = sigm(pwf + pt6);
        const float f1 = sigm(pwf + pt7);
        PFETCH(s + 1);
        float cn = (f0 + f1) * c + sigm(ii) * tanh_f(ch);
        cn = fminf(fmaxf(cn, -100.f), 100.f);
        float hh = sigm(oo) * tanh_f(cn);
        hh = fminf(fmaxf(hh, -100.f), 100.f);
        float l0 = MmatL[tid] * hh, l1 = MmatL[512 + tid] * hh;
#pragma unroll
        for (int off = 32; off > 0; off >>= 1) {
          l0 += __shfl_down(l0, off);
          l1 += __shfl_down(l1, off);
        }
        if ((tid & 63) == 0) { red0[tid >> 6] = l0; red1[tid >> 6] = l1; }
        __syncthreads();
        if (tid == 0) {
          float L0 = mbvL[0], L1 = mbvL[1];
#pragma unroll
          for (int wv = 0; wv < 8; ++wv) { L0 += red0[wv]; L1 += red1[wv]; }
          float mx = fmaxf(L0, L1);
          float e0 = __expf(L0 - mx), e1 = __expf(L1 - mx);
          float inv = 1.f / (e0 + e1);
          const float o0 = e0 * inv, o1 = e1 * inv;
          bcast[0] = o0; bcast[1] = o1;
          pstL[tgt] = o1;
          P_out[((size_t)b * NNODE + tgt) * 2 + 0] = o0;
          P_out[((size_t)b * NNODE + tgt) * 2 + 1] = o1;
        }
        __syncthreads();
        c = cn;
        const bool pub = (bcast[1] > 0.5f) && (tgt < NEnt + 32);
        if (pub) {
          __hip_atomic_store(&hbuf[(size_t)e * HH2 + tid], hh, __ATOMIC_RELAXED, SCOPE_AGENT);
          __syncthreads();
          if (tid == 0) {
            evtofL[tgt - NEnt] = (int)e;
            __hip_atomic_store(&slotbase[e], (uint32_t)(((uint32_t)tgt * BATCH + (uint32_t)b) * NROWS),
                               __ATOMIC_RELAXED, SCOPE_AGENT);
            __hip_atomic_store(head, e + 1u, __ATOMIC_RELEASE, SCOPE_AGENT);
          }
          ++e;
          __syncthreads();
        }
      } else {
        PFETCH(s + 1);
        if (tid == 0) {
          const float o0 = valid ? 0.999f : ((tgt < NEnt) ? 0.001f : 0.f);
          const float o1 = valid ? 0.001f : ((tgt < NEnt) ? 0.999f : 0.f);
          if (valid || tgt >= NEnt) {
            P_out[((size_t)b * NNODE + tgt) * 2 + 0] = o0;
            P_out[((size_t)b * NNODE + tgt) * 2 + 1] = o1;
          }
          if (valid) pstL[tgt] = o1;
        }
        __syncthreads();
      }
    }
#undef PFETCH
  }
  if (tid == 0) {
    __hip_atomic_store(&slotbase[e], TERMEVT, __ATOMIC_RELAXED, SCOPE_AGENT);
    __hip_atomic_store(head, e + 1u, __ATOMIC_RELEASE, SCOPE_AGENT);
  }
}

// ---------------------------------------------------------------------------
extern "C" void kernel_launch(void* const* d_in, const int* in_sizes, int n_in,
                              void* d_out, int out_size, void* d_ws, size_t ws_size,
                              hipStream_t stream)
{
  const int* tokens = (const int*)d_in[0];
  const int* spans  = (const int*)d_in[1];
  const int* enames = (const int*)d_in[2];
  const int* T      = (const int*)d_in[5];
  const int* S      = (const int*)d_in[6];
  const int* entsz  = (const int*)d_in[7];
  const float* word_emb = (const float*)d_in[8];
  const float* elem_emb = (const float*)d_in[9];
  const float* attn_w = (const float*)d_in[10];
  const float* attn_b = (const float*)d_in[11];
  const float* Wih_f = (const float*)d_in[12];
  const float* Whh_f = (const float*)d_in[13];
  const float* bl_f  = (const float*)d_in[14];
  const float* Wih_b = (const float*)d_in[15];
  const float* Whh_b = (const float*)d_in[16];
  const float* bl_b  = (const float*)d_in[17];
  const float* W_ioc = (const float*)d_in[18];
  const float* U_ioc = (const float*)d_in[19];
  const float* b_ioc = (const float*)d_in[20];
  const float* Wf    = (const float*)d_in[21];
  const float* Uf    = (const float*)d_in[22];
  const float* bf    = (const float*)d_in[23];
  const float* W1    = (const float*)d_in[24];
  const float* b1    = (const float*)d_in[25];
  const float* W2    = (const float*)d_in[26];
  const float* b2    = (const float*)d_in[27];
  float* P_out = (float*)d_out;

  char* ws = (char*)d_ws;
  uint32_t* head     = (uint32_t*)ws;                    // @0
  uint32_t* slotbase = (uint32_t*)(ws + 8192);           // 1024 u32
  uint32_t* arrive   = (uint32_t*)(ws + 16384);          // 8*1024 u32 = 32KB
  float* fws = (float*)(ws + 65536);
  size_t off = 0;
  float* Xg    = fws + off; off += (size_t)16384 * 2048;
  float* blstm = fws + off; off += (size_t)SEQB * BATCH * HH2;
  float* attnv = fws + off; off += (size_t)SEQB * BATCH;
  float* Hent  = fws + off; off += (size_t)2048 * 512;
  float* Tall  = fws + off; off += (size_t)96 * BATCH * NROWS;
  unsigned long long* hxbuf = (unsigned long long*)(fws + off);
  off += (size_t)2 * 64 * 256 * 2;           // qwords = 2 floats each
  float* Ucat  = fws + off; off += (size_t)NROWS * 512;
  float* WiocE = fws + off; off += (size_t)128 * 1536;
  float* WfE   = fws + off; off += (size_t)128 * 512;
  float* Mmat  = fws + off; off += 1024;
  float* mbv   = fws + off; off += 16;
  float* hbuf  = fws + off; off += (size_t)1024 * 512;
  const size_t needed = 65536 + off * sizeof(float);
  if (ws_size < needed) return;   // workspace too small: bail (visible failure)

  hipMemsetAsync(d_ws, 0, 65536, stream);
  // hxbuf must start as tag=0/value=0 (valid "h=0 at step 0" records)
  hipMemsetAsync(hxbuf, 0, (size_t)2 * 64 * 256 * 8, stream);

  // 1) Xg = gather(word_emb, tokens) @ [Wih_f;Wih_b].T + [bl_f;bl_b]
  gemm_tn<1><<<dim3(2048 / 64, 16384 / 64), 256, 0, stream>>>(
      nullptr, tokens, word_emb, Wih_f, Wih_b, 1024, bl_f, bl_b, 1024,
      Xg, 16384, 2048, 256);

  // 2) recurrent BiLSTM (element-split, tagged h exchange, resident weights)
  lstm_esplit<<<128, 512, 0, stream>>>(Xg, Whh_f, Whh_b, hxbuf, blstm);

  // 3) attention scores + entity H
  attn_k<<<4096, 256, 0, stream>>>(blstm, attn_w, attn_b, attnv);
  entity_prep<<<2048, 64, 0, stream>>>(spans, attnv, blstm, Hent, P_out);

  // 4) DAG-LSTM precompute
  pack_ucat<<<NROWS, 128, 0, stream>>>(U_ioc, Uf, Ucat);
  elem_pre<<<128, 256, 0, stream>>>(W_ioc, b_ioc, Wf, bf, elem_emb, WiocE, WfE);
  mprep<<<1, 256, 0, stream>>>(W1, b1, W2, b2, Mmat, mbv);
  gemm_tn<0><<<dim3(NROWS / 64, 2048 / 64), 256, 0, stream>>>(
      Hent, nullptr, nullptr, Ucat, nullptr, 0x40000000, nullptr, nullptr, 0,
      Tall, 2048, NROWS, 512);

  // 5) sequential DAG-LSTM with helper projection grid
  dag_seq<<<NHELP + 1, 512, 0, stream>>>(S, T, enames, entsz, WiocE, WfE, Mmat, mbv,
                                         Tall, hbuf, head, slotbase, arrive, Ucat, P_out);
}